// Round 1
// baseline (198.837 us; speedup 1.0000x reference)
//
#include <hip/hip_runtime.h>

#define BINS 128
#define FEAT 64
#define SEG (BINS * FEAT)   // 8192 counters per (b)-histogram
#define B_DIM 32
#define S_DIM 16384
#define CHUNKS 16           // S-chunks per batch
#define THREADS 512         // 8 waves
#define UNROLL 8

// grid = (CHUNKS, B_DIM), block = THREADS.
// Each block: LDS uint histogram over its S-chunk, then global u32 atomic
// merge into d_out (reinterpreted as uint counts).
__global__ __launch_bounds__(THREADS, 2)
void hist_kernel(const float* __restrict__ x, unsigned* out) {
    __shared__ unsigned hist[SEG];
    for (int i = threadIdx.x; i < SEG; i += THREADS) hist[i] = 0u;
    __syncthreads();

    const int b    = blockIdx.y;
    const int lane = threadIdx.x & 63;
    const int wave = threadIdx.x >> 6;                 // 0..7
    const int chunk = S_DIM / CHUNKS;                  // 1024 rows per block
    const int rows_per_wave = chunk / (THREADS / 64);  // 128

    const float* xb = x + (long long)b * S_DIM * FEAT;
    const int s0 = blockIdx.x * chunk + wave * rows_per_wave;

    for (int it = 0; it < rows_per_wave; it += UNROLL) {
        float v[UNROLL];
        #pragma unroll
        for (int u = 0; u < UNROLL; ++u)
            v[u] = xb[(s0 + it + u) * FEAT + lane];    // coalesced 256B/wave/load
        #pragma unroll
        for (int u = 0; u < UNROLL; ++u) {
            int bin = (int)(v[u] * 128.0f);            // exact: x*2^7, trunc like ref
            bin = bin < 0 ? 0 : (bin > 127 ? 127 : bin);
            // addr = bin*64 + lane -> distinct addr per lane, bank = lane%32 (free 2-way)
            atomicAdd(&hist[(bin << 6) + lane], 1u);   // ds_add_u32
        }
    }
    __syncthreads();

    unsigned* gout = out + (size_t)b * SEG;            // out[b][bin][f] matches hist layout
    for (int i = threadIdx.x; i < SEG; i += THREADS) {
        unsigned c = hist[i];
        if (c) atomicAdd(&gout[i], c);                 // global_atomic_add u32
    }
}

// In-place: read uint count, write float count * weight.
// cnt and out alias the same buffer deliberately (no __restrict__!).
__global__ void finalize_kernel(const unsigned* cnt, float* out,
                                const float* __restrict__ w, int n) {
    int i = blockIdx.x * blockDim.x + threadIdx.x;
    if (i < n) {
        unsigned c = cnt[i];
        out[i] = (float)c * w[i & (SEG - 1)];          // weights idx = flat idx mod (bins*F)
    }
}

extern "C" void kernel_launch(void* const* d_in, const int* in_sizes, int n_in,
                              void* d_out, int out_size, void* d_ws, size_t ws_size,
                              hipStream_t stream) {
    const float* x = (const float*)d_in[0];
    const float* w = (const float*)d_in[1];
    float* out = (float*)d_out;

    // d_out is poisoned 0xAA before every call -> zero it (capturable memset node).
    hipMemsetAsync(d_out, 0, (size_t)out_size * sizeof(float), stream);

    dim3 grid(CHUNKS, B_DIM);
    hist_kernel<<<grid, THREADS, 0, stream>>>(x, (unsigned*)d_out);

    int n = out_size;                                   // 262144
    finalize_kernel<<<(n + 255) / 256, 256, 0, stream>>>((const unsigned*)d_out, out, w, n);
}